// Round 1
// baseline (1071.770 us; speedup 1.0000x reference)
//
#include <hip/hip_runtime.h>
#include <math.h>

#define B_   128
#define S_   1024
#define DIN  1024
#define NQ_  8
#define NB_  256
#define ROWS (B_ * S_)  // 131072
#define KT   32         // k-tile width for K1

// ---------------------------------------------------------------------------
// K0: (a) fold the two output GEMMs: W2 = unc_w @ meas_w (256x8),
//         b2 = unc_b + unc_w @ meas_b
//     (b) transpose amp/phase weights k-major: wq[k][0..7]=amp_w[.][k],
//         wq[k][8..15]=phase_w[.][k]  -> one contiguous 64B s_load per k in K1
// ---------------------------------------------------------------------------
__global__ __launch_bounds__(256) void k0_compose(
    const float* __restrict__ meas_w, const float* __restrict__ meas_b,
    const float* __restrict__ unc_w, const float* __restrict__ unc_b,
    const float* __restrict__ amp_w, const float* __restrict__ phase_w,
    float* __restrict__ W2, float* __restrict__ b2, float* __restrict__ wq) {
  int i = threadIdx.x;  // 0..255
  float acc[NQ_] = {0.f, 0.f, 0.f, 0.f, 0.f, 0.f, 0.f, 0.f};
  float accb = 0.f;
  for (int k = 0; k < NB_; ++k) {
    float u = unc_w[i * NB_ + k];
#pragma unroll
    for (int j = 0; j < NQ_; ++j) acc[j] += u * meas_w[k * NQ_ + j];
    accb += u * meas_b[k];
  }
#pragma unroll
  for (int j = 0; j < NQ_; ++j) W2[i * NQ_ + j] = acc[j];
  b2[i] = unc_b[i] + accb;

#pragma unroll
  for (int kk = 0; kk < 4; ++kk) {
    int k = i * 4 + kk;  // 0..1023
#pragma unroll
    for (int j = 0; j < NQ_; ++j) {
      wq[k * 16 + j]     = amp_w[j * DIN + k];
      wq[k * 16 + 8 + j] = phase_w[j * DIN + k];
    }
  }
}

// ---------------------------------------------------------------------------
// K1: per row r of x[131072][1024]: 16 dot products (8 amp + 8 phase),
//     tanh / sigmoid*2pi / sincos -> rp_t, ip_t in TRANSPOSED [S][B][8] layout.
//     x is staged through LDS: global loads are 128B-contiguous per-row
//     segments (8 lanes/row -> full 64B line use, no L1-reuse dependency,
//     no 4KB power-of-2 lane stride). LDS XOR-swizzled (col4 ^ (row&7)) on
//     BOTH write and read -> aligned b128 ops, bijective per row.
//     Weights via scalar path from k-major wq (indices block-uniform).
//     Next tile prefetched into regs during compute (hides ~900cy HBM lat
//     under ~1024cy of FMA per step).
// ---------------------------------------------------------------------------
__global__ __launch_bounds__(256) void k1_proj(
    const float* __restrict__ x, const float* __restrict__ wq,
    const float* __restrict__ amp_b, const float* __restrict__ phase_b,
    float* __restrict__ rp_t, float* __restrict__ ip_t) {
  int tid = threadIdx.x;
  int row0 = blockIdx.x * 256;

  __shared__ float4 tile[256][8];  // 32 KB, [row][physical col4]

  int lr = tid >> 3;             // 0..31: row within 32-row group
  int lc = tid & 7;              // 0..7 : float4 column
  int pc = lc ^ (lr & 7);        // physical col (row&7 == lr&7 since rows step by 32)
  int sw = tid & 7;              // read-side swizzle key for own row

  float acc[16];
#pragma unroll
  for (int j = 0; j < 16; ++j) acc[j] = 0.f;

  const float* xb = x + (size_t)row0 * DIN;
  float4 stg[8];
#pragma unroll
  for (int i = 0; i < 8; ++i)
    stg[i] = *(const float4*)(xb + (size_t)(lr + i * 32) * DIN + lc * 4);

  for (int step = 0; step < DIN / KT; ++step) {
#pragma unroll
    for (int i = 0; i < 8; ++i) tile[lr + i * 32][pc] = stg[i];
    __syncthreads();

    if (step + 1 < DIN / KT) {
      const float* xs = xb + (step + 1) * KT;
#pragma unroll
      for (int i = 0; i < 8; ++i)
        stg[i] = *(const float4*)(xs + (size_t)(lr + i * 32) * DIN + lc * 4);
    }

    const float* wk = wq + step * KT * 16;
#pragma unroll
    for (int c4 = 0; c4 < 8; ++c4) {
      float4 xv = tile[tid][c4 ^ sw];
#pragma unroll
      for (int kk = 0; kk < 4; ++kk) {
        float xk = (kk == 0) ? xv.x : (kk == 1) ? xv.y : (kk == 2) ? xv.z : xv.w;
        const float* w = wk + (c4 * 4 + kk) * 16;
#pragma unroll
        for (int j = 0; j < 8; ++j) {
          acc[j]     += xk * w[j];
          acc[8 + j] += xk * w[8 + j];
        }
      }
    }
    __syncthreads();  // all reads done before next step's overwrite
  }

  float out_r[8], out_i[8];
  const float two_pi = 6.28318530717958647692f;
#pragma unroll
  for (int j = 0; j < 8; ++j) {
    float a  = tanhf(acc[j] + amp_b[j]);
    float ph = two_pi / (1.f + expf(-(acc[8 + j] + phase_b[j])));
    float s, c;
    sincosf(ph, &s, &c);
    out_r[j] = a * c;
    out_i[j] = a * s;
  }
  int row = row0 + tid;
  // transposed layout: [s][b][8], s = row & 1023, b = row >> 10
  size_t toff = ((size_t)(row & (S_ - 1)) * B_ + (size_t)(row >> 10)) * NQ_;
  float4* rp4 = (float4*)(rp_t + toff);
  float4* ip4 = (float4*)(ip_t + toff);
  rp4[0] = make_float4(out_r[0], out_r[1], out_r[2], out_r[3]);
  rp4[1] = make_float4(out_r[4], out_r[5], out_r[6], out_r[7]);
  ip4[0] = make_float4(out_i[0], out_i[1], out_i[2], out_i[3]);
  ip4[1] = make_float4(out_i[4], out_i[5], out_i[6], out_i[7]);
}

// ---------------------------------------------------------------------------
// K2: MHA over L=128 (the B dim) for each n (the S dim), E=8, 4 heads, Dh=2.
//     One block per n (128 threads), both real & imag parts.
//     Inputs/outputs now in transposed [S][B][8] layout -> each block's
//     reads (2x4KB) and write (4KB) are CONTIGUOUS and coalesced.
//     No max-subtraction: |score| <= 11.3, exp safe in fp32.
// ---------------------------------------------------------------------------
__global__ __launch_bounds__(128) void k2_attn(
    const float* __restrict__ rp_t, const float* __restrict__ ip_t,
    const float* __restrict__ in_w, const float* __restrict__ in_b,
    const float* __restrict__ out_w, const float* __restrict__ out_b,
    float* __restrict__ measured_t) {
  int n = blockIdx.x;
  int tid = threadIdx.x;

  __shared__ float q_lds[2][128][9];    // pad 9: stride coprime with 32 banks
  __shared__ float kv_lds[2][128][17];  // [0..7]=k, [8..15]=v, pad 17
  __shared__ float o_lds[2][128][9];

  // ---- stage A: qkv projection, thread = l ----
  {
    int l = tid;
#pragma unroll
    for (int p = 0; p < 2; ++p) {
      const float* src = (p == 0 ? rp_t : ip_t) + ((size_t)n * B_ + l) * NQ_;
      float xv[8];
#pragma unroll
      for (int j = 0; j < 8; ++j) xv[j] = src[j];
#pragma unroll
      for (int c = 0; c < 24; ++c) {
        float acc = in_b[c];
#pragma unroll
        for (int j = 0; j < 8; ++j) acc += in_w[c * 8 + j] * xv[j];
        if (c < 8) q_lds[p][l][c] = acc;
        else       kv_lds[p][l][c - 8] = acc;
      }
    }
  }
  __syncthreads();

  // ---- stage B: attention, thread = (p, h, lb) with 8 rows each ----
  {
    int p = tid >> 6, h = (tid >> 4) & 3, lb = tid & 15;
    float q0[8], q1[8], o0[8], o1[8], ssum[8];
#pragma unroll
    for (int r = 0; r < 8; ++r) {
      q0[r] = q_lds[p][lb * 8 + r][2 * h];
      q1[r] = q_lds[p][lb * 8 + r][2 * h + 1];
      o0[r] = 0.f; o1[r] = 0.f; ssum[r] = 0.f;
    }
    const float scale = 0.70710678118654752440f;  // 1/sqrt(Dh)
    for (int m = 0; m < 128; ++m) {
      float k0 = kv_lds[p][m][2 * h];
      float k1 = kv_lds[p][m][2 * h + 1];
      float v0 = kv_lds[p][m][8 + 2 * h];
      float v1 = kv_lds[p][m][8 + 2 * h + 1];
#pragma unroll
      for (int r = 0; r < 8; ++r) {
        float s = (q0[r] * k0 + q1[r] * k1) * scale;
        float e = expf(s);
        ssum[r] += e;
        o0[r] += e * v0;
        o1[r] += e * v1;
      }
    }
#pragma unroll
    for (int r = 0; r < 8; ++r) {
      float inv = 1.f / ssum[r];
      o_lds[p][lb * 8 + r][2 * h]     = o0[r] * inv;
      o_lds[p][lb * 8 + r][2 * h + 1] = o1[r] * inv;
    }
  }
  __syncthreads();

  // ---- stage C: out_proj + measured, thread = l ----
  {
    int l = tid;
    float res[2][8];
#pragma unroll
    for (int p = 0; p < 2; ++p) {
      float ov[8];
#pragma unroll
      for (int c = 0; c < 8; ++c) ov[c] = o_lds[p][l][c];
#pragma unroll
      for (int j = 0; j < 8; ++j) {
        float acc = out_b[j];
#pragma unroll
        for (int c = 0; c < 8; ++c) acc += out_w[j * 8 + c] * ov[c];
        res[p][j] = acc;
      }
    }
    float* dst = measured_t + ((size_t)n * B_ + l) * NQ_;
#pragma unroll
    for (int j = 0; j < 8; ++j)
      dst[j] = sqrtf(res[0][j] * res[0][j] + res[1][j] * res[1][j]);
  }
}

// ---------------------------------------------------------------------------
// K3: per row: compressed[i] = m . meas_w[i] + meas_b[i]  (out0)
//              uncertainty[i] = sigmoid(m . W2[i] + b2[i]) (out1)
//     Thread = i (256), 64 rows per block. measured_t row address is
//     block-uniform (scalar path); stores fully coalesced. Write-bound.
// ---------------------------------------------------------------------------
__global__ __launch_bounds__(256) void k3_out(
    const float* __restrict__ measured_t,
    const float* __restrict__ meas_w, const float* __restrict__ meas_b,
    const float* __restrict__ W2, const float* __restrict__ b2,
    float* __restrict__ out_c, float* __restrict__ out_u) {
  int i = threadIdx.x;
  float w1[8], w2[8];
#pragma unroll
  for (int j = 0; j < 8; ++j) {
    w1[j] = meas_w[i * 8 + j];
    w2[j] = W2[i * 8 + j];
  }
  float b1 = meas_b[i], bu = b2[i];
  int r0 = blockIdx.x * 64;
  for (int rr = 0; rr < 64; ++rr) {
    int r = r0 + rr;
    // transposed layout: row r lives at [s=r&1023][b=r>>10]
    const float* m = measured_t +
        ((size_t)(r & (S_ - 1)) * B_ + (size_t)(r >> 10)) * NQ_;  // uniform -> s_load
    float mv[8];
#pragma unroll
    for (int j = 0; j < 8; ++j) mv[j] = m[j];
    float c = b1, u = bu;
#pragma unroll
    for (int j = 0; j < 8; ++j) {
      c += w1[j] * mv[j];
      u += w2[j] * mv[j];
    }
    out_c[(size_t)r * NB_ + i] = c;
    out_u[(size_t)r * NB_ + i] = 1.f / (1.f + expf(-u));
  }
}

// ---------------------------------------------------------------------------
extern "C" void kernel_launch(void* const* d_in, const int* in_sizes, int n_in,
                              void* d_out, int out_size, void* d_ws, size_t ws_size,
                              hipStream_t stream) {
  (void)in_sizes; (void)n_in; (void)out_size; (void)ws_size;
  const float* x       = (const float*)d_in[0];
  const float* amp_w   = (const float*)d_in[1];
  const float* amp_b   = (const float*)d_in[2];
  const float* phase_w = (const float*)d_in[3];
  const float* phase_b = (const float*)d_in[4];
  const float* in_w    = (const float*)d_in[5];
  const float* in_b    = (const float*)d_in[6];
  const float* out_w   = (const float*)d_in[7];
  const float* out_b   = (const float*)d_in[8];
  const float* meas_w  = (const float*)d_in[9];
  const float* meas_b  = (const float*)d_in[10];
  const float* unc_w   = (const float*)d_in[11];
  const float* unc_b   = (const float*)d_in[12];

  float* ws         = (float*)d_ws;
  float* rp_t       = ws;                    // 131072*8  [S][B][8]
  float* ip_t       = rp_t + 1048576;        // 131072*8
  float* measured_t = ip_t + 1048576;        // 131072*8
  float* W2         = measured_t + 1048576;  // 256*8
  float* b2         = W2 + 2048;             // 256
  float* wq         = b2 + 256;              // 1024*16 k-major weights
  float* out_c      = (float*)d_out;
  float* out_u      = out_c + (size_t)ROWS * NB_;

  hipLaunchKernelGGL(k0_compose, dim3(1), dim3(256), 0, stream,
                     meas_w, meas_b, unc_w, unc_b, amp_w, phase_w, W2, b2, wq);
  hipLaunchKernelGGL(k1_proj, dim3(ROWS / 256), dim3(256), 0, stream,
                     x, wq, amp_b, phase_b, rp_t, ip_t);
  hipLaunchKernelGGL(k2_attn, dim3(S_), dim3(128), 0, stream,
                     rp_t, ip_t, in_w, in_b, out_w, out_b, measured_t);
  hipLaunchKernelGGL(k3_out, dim3(ROWS / 64), dim3(256), 0, stream,
                     measured_t, meas_w, meas_b, W2, b2, out_c, out_u);
}